// Round 14
// baseline (237.969 us; speedup 1.0000x reference)
//
#include <hip/hip_runtime.h>
#include <hip/hip_bf16.h>
#include <stdint.h>

#define NB  4
#define SEQ 2048
#define DIM 1024
#define NH  16
#define DHD 64
#define LOG2E 1.44269504088896340736f

typedef short short8 __attribute__((ext_vector_type(8)));
typedef float f32x4  __attribute__((ext_vector_type(4)));

__device__ __forceinline__ unsigned short f2bf(float f) {
  union { float f; uint32_t u; } x; x.f = f;
  uint32_t u = x.u;
  uint32_t r = (u + 0x7fffu + ((u >> 16) & 1u)) >> 16;  // RNE
  return (unsigned short)r;
}

__device__ __forceinline__ uint32_t cvt_pk_bf16(float lo, float hi) {
  uint32_t r;
  asm("v_cvt_pk_bf16_f32 %0, %1, %2" : "=v"(r) : "v"(lo), "v"(hi));
  return r;
}

// async global->LDS, 16B per lane (dest wave-linear: base + lane*16)
__device__ __forceinline__ void gload16(const void* g, void* l) {
  __builtin_amdgcn_global_load_lds(
      (const __attribute__((address_space(1))) uint32_t*)g,
      (__attribute__((address_space(3))) uint32_t*)l, 16, 0, 0);
}

// ---------------------------------------------------------------- converts
__global__ void cvt_f32_bf16(const float* __restrict__ in,
                             unsigned short* __restrict__ out, int n4) {
  int i = blockIdx.x * blockDim.x + threadIdx.x;
  int stride = gridDim.x * blockDim.x;
  for (int j = i; j < n4; j += stride) {
    float4 v = reinterpret_cast<const float4*>(in)[j];
    ushort4 o;
    o.x = f2bf(v.x); o.y = f2bf(v.y); o.z = f2bf(v.z); o.w = f2bf(v.w);
    reinterpret_cast<ushort4*>(out)[j] = o;
  }
}

__global__ void cvt_w4(const float* __restrict__ w0, const float* __restrict__ w1,
                       const float* __restrict__ w2, const float* __restrict__ w3,
                       unsigned short* __restrict__ o0, unsigned short* __restrict__ o1,
                       unsigned short* __restrict__ o2, unsigned short* __restrict__ o3,
                       int n4) {
  int seg = blockIdx.x >> 8;
  int bid = blockIdx.x & 255;
  const float* in = (seg == 0) ? w0 : (seg == 1) ? w1 : (seg == 2) ? w2 : w3;
  unsigned short* out = (seg == 0) ? o0 : (seg == 1) ? o1 : (seg == 2) ? o2 : o3;
  for (int j = bid * 256 + threadIdx.x; j < n4; j += 65536) {
    float4 v = reinterpret_cast<const float4*>(in)[j];
    ushort4 o;
    o.x = f2bf(v.x); o.y = f2bf(v.y); o.z = f2bf(v.z); o.w = f2bf(v.w);
    reinterpret_cast<ushort4*>(out)[j] = o;
  }
}

// ---------------------------------------------------------------- GEMM (B^T)
// (r11 structure — unchanged)
template <int MODE, int AF32>
__global__ __launch_bounds__(256, 2) void gemm_bt(
    const unsigned short* __restrict__ A,
    const float* __restrict__ Af,
    const unsigned short* __restrict__ Bm,
    const float* __restrict__ bias,
    float* __restrict__ Cf,
    unsigned short* __restrict__ Cb,
    int M, int N, int K, float scale) {
  __shared__ uint4 smem[4096];

  const int tid  = threadIdx.x;
  const int lane = tid & 63;
  const int wid  = tid >> 6;
  const int cpx  = gridDim.x >> 3;
  const int wg   = (blockIdx.x & 7) * cpx + (blockIdx.x >> 3);
  const int nbn  = N >> 7;
  const int bm   = wg / nbn;
  const int bn   = wg % nbn;
  const int wrow = (wid >> 1) * 64;
  const int wcol = (wid & 1) * 64;

  f32x4 acc[4][4] = {};

  const unsigned short* pa[4];
  const float*          paf[4];
  const unsigned short* pb[4];
  uint4* la[4];
  uint4* lb[4];
#pragma unroll
  for (int i = 0; i < 4; ++i) {
    int c   = tid + (i << 8);
    int row = c >> 3;
    int kc  = (c & 7) ^ (row & 7);
    pa[i]  = A  + (size_t)(bm * 128 + row) * K + kc * 8;
    paf[i] = Af + (size_t)(bm * 128 + row) * K + kc * 8;
    pb[i]  = Bm + (size_t)(bn * 128 + row) * K + kc * 8;
    la[i] = smem + c;
    lb[i] = smem + 2048 + c;
  }

  float4 a32[4][2];
  auto loadA_f32 = [&](int kt) {
#pragma unroll
    for (int i = 0; i < 4; ++i) {
      a32[i][0] = *reinterpret_cast<const float4*>(paf[i] + kt * 64);
      a32[i][1] = *reinterpret_cast<const float4*>(paf[i] + kt * 64 + 4);
    }
  };
  auto writeA_bf16 = [&](int buf) {
#pragma unroll
    for (int i = 0; i < 4; ++i) {
      uint4 w;
      w.x = cvt_pk_bf16(a32[i][0].x, a32[i][0].y);
      w.y = cvt_pk_bf16(a32[i][0].z, a32[i][0].w);
      w.z = cvt_pk_bf16(a32[i][1].x, a32[i][1].y);
      w.w = cvt_pk_bf16(a32[i][1].z, a32[i][1].w);
      *(la[i] + buf * 1024) = w;
    }
  };
  auto stageA_g = [&](int kt, int buf) {
#pragma unroll
    for (int i = 0; i < 4; ++i) gload16(pa[i] + kt * 64, la[i] + buf * 1024);
  };
  auto stageB = [&](int kt, int buf) {
#pragma unroll
    for (int i = 0; i < 4; ++i) gload16(pb[i] + kt * 64, lb[i] + buf * 1024);
  };

  if (AF32) { loadA_f32(0); writeA_bf16(0); }
  else      { stageA_g(0, 0); }
  stageB(0, 0);
  __syncthreads();

  const int NT = K >> 6;
  for (int kt = 0; kt < NT; ++kt) {
    const int cur = kt & 1;
    if (kt + 1 < NT) {
      if (AF32) loadA_f32(kt + 1);
      else      stageA_g(kt + 1, cur ^ 1);
      stageB(kt + 1, cur ^ 1);
    }

#pragma unroll
    for (int s = 0; s < 2; ++s) {
      short8 af[4], bfr[4];
#pragma unroll
      for (int mt = 0; mt < 4; ++mt) {
        int row = wrow + mt * 16 + (lane & 15);
        int ch  = ((s << 2) + (lane >> 4)) ^ (row & 7);
        af[mt]  = __builtin_bit_cast(short8, smem[cur * 1024 + row * 8 + ch]);
      }
#pragma unroll
      for (int nt = 0; nt < 4; ++nt) {
        int row = wcol + nt * 16 + (lane & 15);
        int ch  = ((s << 2) + (lane >> 4)) ^ (row & 7);
        bfr[nt] = __builtin_bit_cast(short8, smem[2048 + cur * 1024 + row * 8 + ch]);
      }
      __builtin_amdgcn_s_setprio(1);
#pragma unroll
      for (int mt = 0; mt < 4; ++mt)
#pragma unroll
        for (int nt = 0; nt < 4; ++nt)
          acc[mt][nt] = __builtin_amdgcn_mfma_f32_16x16x32_bf16(af[mt], bfr[nt], acc[mt][nt], 0, 0, 0);
      __builtin_amdgcn_s_setprio(0);
    }

    if (AF32 && kt + 1 < NT) writeA_bf16(cur ^ 1);
    __syncthreads();
  }

  const int rbase = bm * 128 + wrow + (lane >> 4) * 4;
  const int cbase = bn * 128 + wcol + (lane & 15);
#pragma unroll
  for (int nt = 0; nt < 4; ++nt) {
    int col  = cbase + nt * 16;
    float bv = bias[col];
#pragma unroll
    for (int mt = 0; mt < 4; ++mt) {
      if (MODE == 2) {
        int h = col >> 6, dh = col & 63;
        int row0 = rbase + mt * 16;
        int b = row0 >> 11, lq = row0 & 2047;
        uint2 pk;
        pk.x = cvt_pk_bf16((acc[mt][nt][0] + bv) * scale, (acc[mt][nt][1] + bv) * scale);
        pk.y = cvt_pk_bf16((acc[mt][nt][2] + bv) * scale, (acc[mt][nt][3] + bv) * scale);
        *reinterpret_cast<uint2*>(Cb + ((size_t)((b << 4) + h) * DHD + dh) * SEQ + lq) = pk;
      } else {
#pragma unroll
        for (int r = 0; r < 4; ++r) {
          int row = rbase + mt * 16 + r;
          float v = acc[mt][nt][r] + bv;
          if (MODE == 0) {
            Cf[(size_t)row * N + col] = v;
          } else {
            v *= scale;
            int h = col >> 6, dh = col & 63;
            int b = row >> 11, lq = row & 2047;
            Cb[((size_t)((b << 4) + h) * SEQ + lq) * DHD + dh] = f2bf(v);
          }
        }
      }
    }
  }
}

// ---------------------------------------------------------------- attention
// r9 geometry + in-register P, with the key permutation kappa applied on the
// LDS-READ side (K staged in natural coalesced order — fixes r13's +42% FETCH).
// QK^T A-frag for MFMA j reads LDS row rho = kappa(j*16+qloc); chunk swizzle
// f(row) = ((row>>3)&3)*2 + ((row>>1)&1) keeps reads 2-way (free) and is
// applied as the same involution on the staging source chunk (rule #21).
__global__ __launch_bounds__(512, 4) void attn_kernel(
    const unsigned short* __restrict__ Qh,
    const unsigned short* __restrict__ Kh,
    const unsigned short* __restrict__ Vt,
    unsigned short* __restrict__ O) {
  __shared__ uint4 Kls[2][512];
  __shared__ uint4 Vls[2][512];
  __shared__ uint4 Pls[8][32 * 9];   // O-epilogue staging only

  const int tid  = threadIdx.x;
  const int lane = tid & 63;
  const int wid  = tid >> 6;
  const int wg   = (blockIdx.x & 7) * 64 + (blockIdx.x >> 3);
  const int bh   = wg >> 3;
  const int qt   = wg & 7;
  const int qloc = lane & 15;
  const int grp  = lane >> 4;
  const int q7   = qloc & 7;

  const unsigned short* Qb = Qh + (size_t)bh * SEQ * DHD;
  const unsigned short* Kb = Kh + (size_t)bh * SEQ * DHD;
  const unsigned short* Vb = Vt + (size_t)bh * DHD * SEQ;

  // staging: natural row order for BOTH K and V (fully coalesced).
  // K source chunk pre-XORed with f(srow); V with (srow&7).
  const int srow = tid >> 3;
  const int fK   = ((srow >> 3) & 3) * 2 + ((srow >> 1) & 1);
  const unsigned short* pk0 = Kb + (size_t)srow * DHD + ((tid & 7) ^ fK) * 8;
  const unsigned short* pv0 = Vb + (size_t)srow * SEQ + ((tid & 7) ^ (srow & 7)) * 8;
  auto stage = [&](int kt, int buf) {
    gload16(pk0 + (size_t)kt * 64 * DHD, &Kls[buf][tid]);
    gload16(pv0 + kt * 64,               &Vls[buf][tid]);
  };

  stage(0, 0);

  short8 qf[2][2];
#pragma unroll
  for (int qb = 0; qb < 2; ++qb) {
    int qrow = qt * 256 + wid * 32 + qb * 16 + qloc;
#pragma unroll
    for (int s = 0; s < 2; ++s)
      qf[qb][s] = *reinterpret_cast<const short8*>(Qb + (size_t)qrow * DHD + s * 32 + grp * 8);
  }

  const short8 ones = {0x3F80, 0x3F80, 0x3F80, 0x3F80, 0x3F80, 0x3F80, 0x3F80, 0x3F80};
  char* pwb = (char*)&Pls[wid][0];

  __syncthreads();

  float logbias = 0.f;
  f32x4 lsum[2] = {};
  f32x4 acc_o[4][2] = {};

  const int NT = SEQ / 64;
  for (int kt = 0; kt < NT; ++kt) {
    const int cur = kt & 1;
    if (kt + 1 < NT) stage(kt + 1, cur ^ 1);

    // S^T = K Q^T; A-frag rows permuted by kappa so P is lane-local for PV
    f32x4 sc[4][2];
    __builtin_amdgcn_s_setprio(1);
#pragma unroll
    for (int j = 0; j < 4; ++j) {
      // rho = kappa(j*16+qloc) = (j>>1)*32 + (qloc>>2)*8 + (j&1)*4 + (qloc&3)
      int rho = ((j >> 1) << 5) + ((qloc >> 2) << 3) + ((j & 1) << 2) + (qloc & 3);
      int fR  = ((rho >> 3) & 3) * 2 + ((rho >> 1) & 1);
      short8 kf[2];
#pragma unroll
      for (int s = 0; s < 2; ++s) {
        int ch = ((s << 2) + grp) ^ fR;
        kf[s] = __builtin_bit_cast(short8, Kls[cur][rho * 8 + ch]);
      }
#pragma unroll
      for (int qb = 0; qb < 2; ++qb) {
        f32x4 a = {logbias, logbias, logbias, logbias};
        a = __builtin_amdgcn_mfma_f32_16x16x32_bf16(kf[0], qf[qb][0], a, 0, 0, 0);
        a = __builtin_amdgcn_mfma_f32_16x16x32_bf16(kf[1], qf[qb][1], a, 0, 0, 0);
        sc[j][qb] = a;
      }
    }
    __builtin_amdgcn_s_setprio(0);

    // V-frags once (shared by both qb); natural key indexing
    short8 vf[4][2];
#pragma unroll
    for (int db = 0; db < 4; ++db)
#pragma unroll
      for (int t = 0; t < 2; ++t) {
        int vrow = db * 16 + qloc;
        int ch   = ((t << 2) + grp) ^ q7;
        vf[db][t] = __builtin_bit_cast(short8, Vls[cur][vrow * 8 + ch]);
      }

    // per qb: P = exp2(S) packed in-register (keys lane-local), PV + lsum
#pragma unroll
    for (int qb = 0; qb < 2; ++qb) {
      uint4 p0, p1;
      p0.x = cvt_pk_bf16(exp2f(sc[0][qb][0]), exp2f(sc[0][qb][1]));
      p0.y = cvt_pk_bf16(exp2f(sc[0][qb][2]), exp2f(sc[0][qb][3]));
      p0.z = cvt_pk_bf16(exp2f(sc[1][qb][0]), exp2f(sc[1][qb][1]));
      p0.w = cvt_pk_bf16(exp2f(sc[1][qb][2]), exp2f(sc[1][qb][3]));
      p1.x = cvt_pk_bf16(exp2f(sc[2][qb][0]), exp2f(sc[2][qb][1]));
      p1.y = cvt_pk_bf16(exp2f(sc[2][qb][2]), exp2f(sc[2][qb][3]));
      p1.z = cvt_pk_bf16(exp2f(sc[3][qb][0]), exp2f(sc[3][qb][1]));
      p1.w = cvt_pk_bf16(exp2f(sc[3][qb][2]), exp2f(sc[3][qb][3]));
      short8 pf0 = __builtin_bit_cast(short8, p0);  // keys grp*8+0..7   (t=0)
      short8 pf1 = __builtin_bit_cast(short8, p1);  // keys 32+grp*8+0..7 (t=1)
      __builtin_amdgcn_s_setprio(1);
#pragma unroll
      for (int db = 0; db < 4; ++db) {
        acc_o[db][qb] = __builtin_amdgcn_mfma_f32_16x16x32_bf16(vf[db][0], pf0, acc_o[db][qb], 0, 0, 0);
        acc_o[db][qb] = __builtin_amdgcn_mfma_f32_16x16x32_bf16(vf[db][1], pf1, acc_o[db][qb], 0, 0, 0);
      }
      lsum[qb] = __builtin_amdgcn_mfma_f32_16x16x32_bf16(ones, pf0, lsum[qb], 0, 0, 0);
      lsum[qb] = __builtin_amdgcn_mfma_f32_16x16x32_bf16(ones, pf1, lsum[qb], 0, 0, 0);
      __builtin_amdgcn_s_setprio(0);
    }

    if (__any(fmaxf(lsum[0][0], lsum[1][0]) > 7.9e28f)) {
      const float ds = 5.421010862e-20f;  // 2^-64
      logbias -= 64.f;
#pragma unroll
      for (int db = 0; db < 4; ++db)
#pragma unroll
        for (int qb = 0; qb < 2; ++qb)
#pragma unroll
          for (int r = 0; r < 4; ++r) acc_o[db][qb][r] *= ds;
#pragma unroll
      for (int qb = 0; qb < 2; ++qb)
#pragma unroll
        for (int r = 0; r < 4; ++r) lsum[qb][r] *= ds;
    }

    __syncthreads();
  }

  const float inv0 = 1.0f / lsum[0][0];
  const float inv1 = 1.0f / lsum[1][0];
#pragma unroll
  for (int db = 0; db < 4; ++db)
#pragma unroll
    for (int qb = 0; qb < 2; ++qb) {
      float inv = qb ? inv1 : inv0;
      uint2 w;
      w.x = cvt_pk_bf16(acc_o[db][qb][0] * inv, acc_o[db][qb][1] * inv);
      w.y = cvt_pk_bf16(acc_o[db][qb][2] * inv, acc_o[db][qb][3] * inv);
      *(uint2*)(pwb + (qb * 16 + qloc) * 144 + db * 32 + grp * 8) = w;
    }
  const int b = bh >> 4, h = bh & 15;
#pragma unroll
  for (int pass = 0; pass < 4; ++pass) {
    int idx = pass * 64 + lane;
    int row = idx >> 3;
    int ck  = idx & 7;
    uint4 val = *(const uint4*)(pwb + row * 144 + ck * 16);
    int rowg  = qt * 256 + wid * 32 + row;
    *reinterpret_cast<uint4*>(O + ((size_t)(b * SEQ + rowg)) * DIM + (h << 6) + ck * 8) = val;
  }
}

// ---------------------------------------------------------------- launch
extern "C" void kernel_launch(void* const* d_in, const int* in_sizes, int n_in,
                              void* d_out, int out_size, void* d_ws, size_t ws_size,
                              hipStream_t stream) {
  (void)in_sizes; (void)n_in; (void)out_size;
  const float* q  = (const float*)d_in[0];
  const float* k  = (const float*)d_in[1];
  const float* v  = (const float*)d_in[2];
  const float* Wq = (const float*)d_in[3];
  const float* bq = (const float*)d_in[4];
  const float* Wk = (const float*)d_in[5];
  const float* bk = (const float*)d_in[6];
  const float* Wv = (const float*)d_in[7];
  const float* bv = (const float*)d_in[8];
  const float* Wo = (const float*)d_in[9];
  const float* bo = (const float*)d_in[10];
  float* out = (float*)d_out;

  char* ws = (char*)d_ws;
  const size_t MB = 1024 * 1024;
  const int nW = DIM * DIM;
  const int M  = NB * SEQ;
  dim3 gg((M / 128) * (DIM / 128));            // 512 blocks
  const int attnGrid = NB * NH * (SEQ / 256);  // 512 blocks

  if (ws_size >= 73 * MB) {
    unsigned short* X   = (unsigned short*)(ws + 0);
    unsigned short* WXq = (unsigned short*)(ws + 16 * MB);
    unsigned short* WXk = (unsigned short*)(ws + 18 * MB);
    unsigned short* WXv = (unsigned short*)(ws + 20 * MB);
    unsigned short* WXo = (unsigned short*)(ws + 22 * MB);
    unsigned short* Qhp = (unsigned short*)(ws + 24 * MB);
    unsigned short* Khp = (unsigned short*)(ws + 40 * MB);
    unsigned short* Vtp = (unsigned short*)(ws + 56 * MB);

    cvt_w4<<<1024, 256, 0, stream>>>(Wq, Wk, Wv, Wo, WXq, WXk, WXv, WXo, nW / 4);
    gemm_bt<1, 1><<<gg, 256, 0, stream>>>(nullptr, q, WXq, bq, nullptr, Qhp, M, DIM, DIM, 0.125f * LOG2E);
    gemm_bt<1, 1><<<gg, 256, 0, stream>>>(nullptr, k, WXk, bk, nullptr, Khp, M, DIM, DIM, 1.0f);
    gemm_bt<2, 1><<<gg, 256, 0, stream>>>(nullptr, v, WXv, bv, nullptr, Vtp, M, DIM, DIM, 1.0f);
    attn_kernel<<<attnGrid, 512, 0, stream>>>(Qhp, Khp, Vtp, X);
    gemm_bt<0, 0><<<gg, 256, 0, stream>>>(X, nullptr, WXo, bo, out, nullptr, M, DIM, DIM, 1.0f);
  } else {
    unsigned short* X   = (unsigned short*)(ws + 0);
    unsigned short* WX  = (unsigned short*)(ws + 16 * MB);
    unsigned short* Qhp = (unsigned short*)(ws + 18 * MB);
    unsigned short* Khp = (unsigned short*)(ws + 34 * MB);
    unsigned short* Vtp = (unsigned short*)(ws + 50 * MB);

    cvt_f32_bf16<<<1024, 256, 0, stream>>>(Wq, WX, nW / 4);
    gemm_bt<1, 1><<<gg, 256, 0, stream>>>(nullptr, q, WX, bq, nullptr, Qhp, M, DIM, DIM, 0.125f * LOG2E);
    cvt_f32_bf16<<<1024, 256, 0, stream>>>(Wk, WX, nW / 4);
    gemm_bt<1, 1><<<gg, 256, 0, stream>>>(nullptr, k, WX, bk, nullptr, Khp, M, DIM, DIM, 1.0f);
    cvt_f32_bf16<<<1024, 256, 0, stream>>>(Wv, WX, nW / 4);
    gemm_bt<2, 1><<<gg, 256, 0, stream>>>(nullptr, v, WX, bv, nullptr, Vtp, M, DIM, DIM, 1.0f);
    attn_kernel<<<attnGrid, 512, 0, stream>>>(Qhp, Khp, Vtp, X);
    cvt_f32_bf16<<<1024, 256, 0, stream>>>(Wo, WX, nW / 4);
    gemm_bt<0, 0><<<gg, 256, 0, stream>>>(X, nullptr, WX, bo, out, nullptr, M, DIM, DIM, 1.0f);
  }
}

// Round 15
// 210.869 us; speedup vs baseline: 1.1285x; 1.1285x over previous
//
#include <hip/hip_runtime.h>
#include <hip/hip_bf16.h>
#include <stdint.h>

#define NB  4
#define SEQ 2048
#define DIM 1024
#define NH  16
#define DHD 64
#define LOG2E 1.44269504088896340736f

typedef short short8 __attribute__((ext_vector_type(8)));
typedef float f32x4  __attribute__((ext_vector_type(4)));

__device__ __forceinline__ unsigned short f2bf(float f) {
  union { float f; uint32_t u; } x; x.f = f;
  uint32_t u = x.u;
  uint32_t r = (u + 0x7fffu + ((u >> 16) & 1u)) >> 16;  // RNE
  return (unsigned short)r;
}

__device__ __forceinline__ uint32_t cvt_pk_bf16(float lo, float hi) {
  uint32_t r;
  asm("v_cvt_pk_bf16_f32 %0, %1, %2" : "=v"(r) : "v"(lo), "v"(hi));
  return r;
}

// async global->LDS, 16B per lane (dest wave-linear: base + lane*16)
__device__ __forceinline__ void gload16(const void* g, void* l) {
  __builtin_amdgcn_global_load_lds(
      (const __attribute__((address_space(1))) uint32_t*)g,
      (__attribute__((address_space(3))) uint32_t*)l, 16, 0, 0);
}

// ---------------------------------------------------------------- converts
__global__ void cvt_f32_bf16(const float* __restrict__ in,
                             unsigned short* __restrict__ out, int n4) {
  int i = blockIdx.x * blockDim.x + threadIdx.x;
  int stride = gridDim.x * blockDim.x;
  for (int j = i; j < n4; j += stride) {
    float4 v = reinterpret_cast<const float4*>(in)[j];
    ushort4 o;
    o.x = f2bf(v.x); o.y = f2bf(v.y); o.z = f2bf(v.z); o.w = f2bf(v.w);
    reinterpret_cast<ushort4*>(out)[j] = o;
  }
}

__global__ void cvt_w4(const float* __restrict__ w0, const float* __restrict__ w1,
                       const float* __restrict__ w2, const float* __restrict__ w3,
                       unsigned short* __restrict__ o0, unsigned short* __restrict__ o1,
                       unsigned short* __restrict__ o2, unsigned short* __restrict__ o3,
                       int n4) {
  int seg = blockIdx.x >> 8;
  int bid = blockIdx.x & 255;
  const float* in = (seg == 0) ? w0 : (seg == 1) ? w1 : (seg == 2) ? w2 : w3;
  unsigned short* out = (seg == 0) ? o0 : (seg == 1) ? o1 : (seg == 2) ? o2 : o3;
  for (int j = bid * 256 + threadIdx.x; j < n4; j += 65536) {
    float4 v = reinterpret_cast<const float4*>(in)[j];
    ushort4 o;
    o.x = f2bf(v.x); o.y = f2bf(v.y); o.z = f2bf(v.z); o.w = f2bf(v.w);
    reinterpret_cast<ushort4*>(out)[j] = o;
  }
}

// ---------------------------------------------------------------- GEMM (B^T)
// r11 structure. MODE 0: fp32 direct; MODE 1: bf16 head-split via LDS
// transpose epilogue (fixes 2B-store 4x write amplification; path verified
// r7); MODE 2: bf16 head-transposed, 8B direct stores.
template <int MODE, int AF32>
__global__ __launch_bounds__(256, 2) void gemm_bt(
    const unsigned short* __restrict__ A,
    const float* __restrict__ Af,
    const unsigned short* __restrict__ Bm,
    const float* __restrict__ bias,
    float* __restrict__ Cf,
    unsigned short* __restrict__ Cb,
    int M, int N, int K, float scale) {
  __shared__ uint4 smem[4096];

  const int tid  = threadIdx.x;
  const int lane = tid & 63;
  const int wid  = tid >> 6;
  const int cpx  = gridDim.x >> 3;
  const int wg   = (blockIdx.x & 7) * cpx + (blockIdx.x >> 3);
  const int nbn  = N >> 7;
  const int bm   = wg / nbn;
  const int bn   = wg % nbn;
  const int wrow = (wid >> 1) * 64;
  const int wcol = (wid & 1) * 64;

  f32x4 acc[4][4] = {};

  const unsigned short* pa[4];
  const float*          paf[4];
  const unsigned short* pb[4];
  uint4* la[4];
  uint4* lb[4];
#pragma unroll
  for (int i = 0; i < 4; ++i) {
    int c   = tid + (i << 8);
    int row = c >> 3;
    int kc  = (c & 7) ^ (row & 7);
    pa[i]  = A  + (size_t)(bm * 128 + row) * K + kc * 8;
    paf[i] = Af + (size_t)(bm * 128 + row) * K + kc * 8;
    pb[i]  = Bm + (size_t)(bn * 128 + row) * K + kc * 8;
    la[i] = smem + c;
    lb[i] = smem + 2048 + c;
  }

  float4 a32[4][2];
  auto loadA_f32 = [&](int kt) {
#pragma unroll
    for (int i = 0; i < 4; ++i) {
      a32[i][0] = *reinterpret_cast<const float4*>(paf[i] + kt * 64);
      a32[i][1] = *reinterpret_cast<const float4*>(paf[i] + kt * 64 + 4);
    }
  };
  auto writeA_bf16 = [&](int buf) {
#pragma unroll
    for (int i = 0; i < 4; ++i) {
      uint4 w;
      w.x = cvt_pk_bf16(a32[i][0].x, a32[i][0].y);
      w.y = cvt_pk_bf16(a32[i][0].z, a32[i][0].w);
      w.z = cvt_pk_bf16(a32[i][1].x, a32[i][1].y);
      w.w = cvt_pk_bf16(a32[i][1].z, a32[i][1].w);
      *(la[i] + buf * 1024) = w;
    }
  };
  auto stageA_g = [&](int kt, int buf) {
#pragma unroll
    for (int i = 0; i < 4; ++i) gload16(pa[i] + kt * 64, la[i] + buf * 1024);
  };
  auto stageB = [&](int kt, int buf) {
#pragma unroll
    for (int i = 0; i < 4; ++i) gload16(pb[i] + kt * 64, lb[i] + buf * 1024);
  };

  if (AF32) { loadA_f32(0); writeA_bf16(0); }
  else      { stageA_g(0, 0); }
  stageB(0, 0);
  __syncthreads();

  const int NT = K >> 6;
  for (int kt = 0; kt < NT; ++kt) {
    const int cur = kt & 1;
    if (kt + 1 < NT) {
      if (AF32) loadA_f32(kt + 1);
      else      stageA_g(kt + 1, cur ^ 1);
      stageB(kt + 1, cur ^ 1);
    }

#pragma unroll
    for (int s = 0; s < 2; ++s) {
      short8 af[4], bfr[4];
#pragma unroll
      for (int mt = 0; mt < 4; ++mt) {
        int row = wrow + mt * 16 + (lane & 15);
        int ch  = ((s << 2) + (lane >> 4)) ^ (row & 7);
        af[mt]  = __builtin_bit_cast(short8, smem[cur * 1024 + row * 8 + ch]);
      }
#pragma unroll
      for (int nt = 0; nt < 4; ++nt) {
        int row = wcol + nt * 16 + (lane & 15);
        int ch  = ((s << 2) + (lane >> 4)) ^ (row & 7);
        bfr[nt] = __builtin_bit_cast(short8, smem[2048 + cur * 1024 + row * 8 + ch]);
      }
      __builtin_amdgcn_s_setprio(1);
#pragma unroll
      for (int mt = 0; mt < 4; ++mt)
#pragma unroll
        for (int nt = 0; nt < 4; ++nt)
          acc[mt][nt] = __builtin_amdgcn_mfma_f32_16x16x32_bf16(af[mt], bfr[nt], acc[mt][nt], 0, 0, 0);
      __builtin_amdgcn_s_setprio(0);
    }

    if (AF32 && kt + 1 < NT) writeA_bf16(cur ^ 1);
    __syncthreads();
  }

  if (MODE == 1) {
    // LDS-transpose epilogue: coalesced 16B stores, dh-contiguous
    unsigned short* cb = (unsigned short*)smem;  // [128 row][128 col] bf16
#pragma unroll
    for (int nt = 0; nt < 4; ++nt) {
      int tcol = wcol + nt * 16 + (lane & 15);
      float bv = bias[bn * 128 + tcol];
#pragma unroll
      for (int mt = 0; mt < 4; ++mt)
#pragma unroll
        for (int r = 0; r < 4; ++r) {
          int trow = wrow + mt * 16 + (lane >> 4) * 4 + r;
          cb[trow * 128 + tcol] = f2bf((acc[mt][nt][r] + bv) * scale);
        }
    }
    __syncthreads();
#pragma unroll
    for (int it = 0; it < 8; ++it) {
      int idx = tid + it * 256;          // 0..2047
      int row = idx >> 4, seg = idx & 15;
      uint4 val = ((uint4*)cb)[idx];
      int gcol = bn * 128 + seg * 8;
      int h = gcol >> 6, dh = gcol & 63;
      int grow = bm * 128 + row;
      int b = grow >> 11, lq = grow & 2047;
      *reinterpret_cast<uint4*>(Cb + ((size_t)((b << 4) + h) * SEQ + lq) * DHD + dh) = val;
    }
  } else {
    const int rbase = bm * 128 + wrow + (lane >> 4) * 4;
    const int cbase = bn * 128 + wcol + (lane & 15);
#pragma unroll
    for (int nt = 0; nt < 4; ++nt) {
      int col  = cbase + nt * 16;
      float bv = bias[col];
#pragma unroll
      for (int mt = 0; mt < 4; ++mt) {
        if (MODE == 2) {
          int h = col >> 6, dh = col & 63;
          int row0 = rbase + mt * 16;
          int b = row0 >> 11, lq = row0 & 2047;
          uint2 pk;
          pk.x = cvt_pk_bf16((acc[mt][nt][0] + bv) * scale, (acc[mt][nt][1] + bv) * scale);
          pk.y = cvt_pk_bf16((acc[mt][nt][2] + bv) * scale, (acc[mt][nt][3] + bv) * scale);
          *reinterpret_cast<uint2*>(Cb + ((size_t)((b << 4) + h) * DHD + dh) * SEQ + lq) = pk;
        } else {
#pragma unroll
          for (int r = 0; r < 4; ++r) {
            int row = rbase + mt * 16 + r;
            Cf[(size_t)row * N + col] = acc[mt][nt][r] + bv;
          }
        }
      }
    }
  }
}

// ---------------------------------------------------------------- attention
// r11-EXACT (113 us, clean counters). r12-r14 restructures (per-qb ordering,
// in-register P) all showed the scratch-spill signature (WRITE_SIZE 112-127MB)
// — this ordering is the only one that fits the register budget.
__global__ __launch_bounds__(512, 4) void attn_kernel(
    const unsigned short* __restrict__ Qh,
    const unsigned short* __restrict__ Kh,
    const unsigned short* __restrict__ Vt,
    unsigned short* __restrict__ O) {
  __shared__ uint4 Kls[2][512];
  __shared__ uint4 Vls[2][512];
  __shared__ uint4 Pls[8][32 * 9];

  const int tid  = threadIdx.x;
  const int lane = tid & 63;
  const int wid  = tid >> 6;
  const int wg   = (blockIdx.x & 7) * 64 + (blockIdx.x >> 3);
  const int bh   = wg >> 3;
  const int qt   = wg & 7;
  const int qloc = lane & 15;
  const int grp  = lane >> 4;
  const int q7   = qloc & 7;

  const unsigned short* Qb = Qh + (size_t)bh * SEQ * DHD;
  const unsigned short* Kb = Kh + (size_t)bh * SEQ * DHD;
  const unsigned short* Vb = Vt + (size_t)bh * DHD * SEQ;

  const int srow = tid >> 3;
  const int skc  = (tid & 7) ^ (srow & 7);
  const unsigned short* pk0 = Kb + (size_t)srow * DHD + skc * 8;
  const unsigned short* pv0 = Vb + (size_t)srow * SEQ + skc * 8;
  auto stage = [&](int kt, int buf) {
    gload16(pk0 + (size_t)kt * 64 * DHD, &Kls[buf][tid]);
    gload16(pv0 + kt * 64,               &Vls[buf][tid]);
  };

  stage(0, 0);

  short8 qf[2][2];
#pragma unroll
  for (int qb = 0; qb < 2; ++qb) {
    int qrow = qt * 256 + wid * 32 + qb * 16 + qloc;
#pragma unroll
    for (int s = 0; s < 2; ++s)
      qf[qb][s] = *reinterpret_cast<const short8*>(Qb + (size_t)qrow * DHD + s * 32 + grp * 8);
  }

  const short8 ones = {0x3F80, 0x3F80, 0x3F80, 0x3F80, 0x3F80, 0x3F80, 0x3F80, 0x3F80};
  char* pwb = (char*)&Pls[wid][0];

  __syncthreads();

  float logbias = 0.f;
  f32x4 lsum[2] = {};
  f32x4 acc_o[4][2] = {};

  const int NT = SEQ / 64;
  for (int kt = 0; kt < NT; ++kt) {
    const int cur = kt & 1;
    if (kt + 1 < NT) stage(kt + 1, cur ^ 1);

    f32x4 sc[4][2];
    __builtin_amdgcn_s_setprio(1);
#pragma unroll
    for (int j = 0; j < 4; ++j) {
      short8 kf[2];
#pragma unroll
      for (int s = 0; s < 2; ++s) {
        int krow = j * 16 + qloc;
        int ch   = ((s << 2) + grp) ^ q7;
        kf[s] = __builtin_bit_cast(short8, Kls[cur][krow * 8 + ch]);
      }
#pragma unroll
      for (int qb = 0; qb < 2; ++qb) {
        f32x4 a = {logbias, logbias, logbias, logbias};
        a = __builtin_amdgcn_mfma_f32_16x16x32_bf16(kf[0], qf[qb][0], a, 0, 0, 0);
        a = __builtin_amdgcn_mfma_f32_16x16x32_bf16(kf[1], qf[qb][1], a, 0, 0, 0);
        sc[j][qb] = a;
      }
    }
    __builtin_amdgcn_s_setprio(0);

#pragma unroll
    for (int j = 0; j < 4; ++j)
#pragma unroll
      for (int qb = 0; qb < 2; ++qb) {
        float p0 = exp2f(sc[j][qb][0]);
        float p1 = exp2f(sc[j][qb][1]);
        float p2 = exp2f(sc[j][qb][2]);
        float p3 = exp2f(sc[j][qb][3]);
        uint2 w;
        w.x = cvt_pk_bf16(p0, p1);
        w.y = cvt_pk_bf16(p2, p3);
        *(uint2*)(pwb + (qb * 16 + qloc) * 144 + j * 32 + grp * 8) = w;
      }

    short8 pf[2][2];
#pragma unroll
    for (int qb = 0; qb < 2; ++qb)
#pragma unroll
      for (int t = 0; t < 2; ++t)
        pf[qb][t] = *(const short8*)(pwb + (qb * 16 + qloc) * 144 + t * 64 + grp * 16);

    __builtin_amdgcn_s_setprio(1);
#pragma unroll
    for (int db = 0; db < 4; ++db) {
      short8 vf[2];
#pragma unroll
      for (int t = 0; t < 2; ++t) {
        int vrow = db * 16 + qloc;
        int ch   = ((t << 2) + grp) ^ q7;
        vf[t] = __builtin_bit_cast(short8, Vls[cur][vrow * 8 + ch]);
      }
#pragma unroll
      for (int qb = 0; qb < 2; ++qb) {
        acc_o[db][qb] = __builtin_amdgcn_mfma_f32_16x16x32_bf16(vf[0], pf[qb][0], acc_o[db][qb], 0, 0, 0);
        acc_o[db][qb] = __builtin_amdgcn_mfma_f32_16x16x32_bf16(vf[1], pf[qb][1], acc_o[db][qb], 0, 0, 0);
      }
    }
#pragma unroll
    for (int qb = 0; qb < 2; ++qb) {
      lsum[qb] = __builtin_amdgcn_mfma_f32_16x16x32_bf16(ones, pf[qb][0], lsum[qb], 0, 0, 0);
      lsum[qb] = __builtin_amdgcn_mfma_f32_16x16x32_bf16(ones, pf[qb][1], lsum[qb], 0, 0, 0);
    }
    __builtin_amdgcn_s_setprio(0);

    if (__any(fmaxf(lsum[0][0], lsum[1][0]) > 7.9e28f)) {
      const float ds = 5.421010862e-20f;  // 2^-64
      logbias -= 64.f;
#pragma unroll
      for (int db = 0; db < 4; ++db)
#pragma unroll
        for (int qb = 0; qb < 2; ++qb)
#pragma unroll
          for (int r = 0; r < 4; ++r) acc_o[db][qb][r] *= ds;
#pragma unroll
      for (int qb = 0; qb < 2; ++qb)
#pragma unroll
        for (int r = 0; r < 4; ++r) lsum[qb][r] *= ds;
    }

    __syncthreads();
  }

  const float inv0 = 1.0f / lsum[0][0];
  const float inv1 = 1.0f / lsum[1][0];
#pragma unroll
  for (int db = 0; db < 4; ++db)
#pragma unroll
    for (int qb = 0; qb < 2; ++qb) {
      float inv = qb ? inv1 : inv0;
      uint2 w;
      w.x = cvt_pk_bf16(acc_o[db][qb][0] * inv, acc_o[db][qb][1] * inv);
      w.y = cvt_pk_bf16(acc_o[db][qb][2] * inv, acc_o[db][qb][3] * inv);
      *(uint2*)(pwb + (qb * 16 + qloc) * 144 + db * 32 + grp * 8) = w;
    }
  const int b = bh >> 4, h = bh & 15;
#pragma unroll
  for (int pass = 0; pass < 4; ++pass) {
    int idx = pass * 64 + lane;
    int row = idx >> 3;
    int ck  = idx & 7;
    uint4 val = *(const uint4*)(pwb + row * 144 + ck * 16);
    int rowg  = qt * 256 + wid * 32 + row;
    *reinterpret_cast<uint4*>(O + ((size_t)(b * SEQ + rowg)) * DIM + (h << 6) + ck * 8) = val;
  }
}

// ---------------------------------------------------------------- launch
extern "C" void kernel_launch(void* const* d_in, const int* in_sizes, int n_in,
                              void* d_out, int out_size, void* d_ws, size_t ws_size,
                              hipStream_t stream) {
  (void)in_sizes; (void)n_in; (void)out_size;
  const float* q  = (const float*)d_in[0];
  const float* k  = (const float*)d_in[1];
  const float* v  = (const float*)d_in[2];
  const float* Wq = (const float*)d_in[3];
  const float* bq = (const float*)d_in[4];
  const float* Wk = (const float*)d_in[5];
  const float* bk = (const float*)d_in[6];
  const float* Wv = (const float*)d_in[7];
  const float* bv = (const float*)d_in[8];
  const float* Wo = (const float*)d_in[9];
  const float* bo = (const float*)d_in[10];
  float* out = (float*)d_out;

  char* ws = (char*)d_ws;
  const size_t MB = 1024 * 1024;
  const int nW = DIM * DIM;
  const int M  = NB * SEQ;
  dim3 gg((M / 128) * (DIM / 128));            // 512 blocks
  const int attnGrid = NB * NH * (SEQ / 256);  // 512 blocks

  if (ws_size >= 73 * MB) {
    unsigned short* X   = (unsigned short*)(ws + 0);
    unsigned short* WXq = (unsigned short*)(ws + 16 * MB);
    unsigned short* WXk = (unsigned short*)(ws + 18 * MB);
    unsigned short* WXv = (unsigned short*)(ws + 20 * MB);
    unsigned short* WXo = (unsigned short*)(ws + 22 * MB);
    unsigned short* Qhp = (unsigned short*)(ws + 24 * MB);
    unsigned short* Khp = (unsigned short*)(ws + 40 * MB);
    unsigned short* Vtp = (unsigned short*)(ws + 56 * MB);

    cvt_w4<<<1024, 256, 0, stream>>>(Wq, Wk, Wv, Wo, WXq, WXk, WXv, WXo, nW / 4);
    gemm_bt<1, 1><<<gg, 256, 0, stream>>>(nullptr, q, WXq, bq, nullptr, Qhp, M, DIM, DIM, 0.125f * LOG2E);
    gemm_bt<1, 1><<<gg, 256, 0, stream>>>(nullptr, k, WXk, bk, nullptr, Khp, M, DIM, DIM, 1.0f);
    gemm_bt<2, 1><<<gg, 256, 0, stream>>>(nullptr, v, WXv, bv, nullptr, Vtp, M, DIM, DIM, 1.0f);
    attn_kernel<<<attnGrid, 512, 0, stream>>>(Qhp, Khp, Vtp, X);
    gemm_bt<0, 0><<<gg, 256, 0, stream>>>(X, nullptr, WXo, bo, out, nullptr, M, DIM, DIM, 1.0f);
  } else {
    unsigned short* X   = (unsigned short*)(ws + 0);
    unsigned short* WX  = (unsigned short*)(ws + 16 * MB);
    unsigned short* Qhp = (unsigned short*)(ws + 18 * MB);
    unsigned short* Khp = (unsigned short*)(ws + 34 * MB);
    unsigned short* Vtp = (unsigned short*)(ws + 50 * MB);

    cvt_f32_bf16<<<1024, 256, 0, stream>>>(Wq, WX, nW / 4);
    gemm_bt<1, 1><<<gg, 256, 0, stream>>>(nullptr, q, WX, bq, nullptr, Qhp, M, DIM, DIM, 0.125f * LOG2E);
    cvt_f32_bf16<<<1024, 256, 0, stream>>>(Wk, WX, nW / 4);
    gemm_bt<1, 1><<<gg, 256, 0, stream>>>(nullptr, k, WX, bk, nullptr, Khp, M, DIM, DIM, 1.0f);
    cvt_f32_bf16<<<1024, 256, 0, stream>>>(Wv, WX, nW / 4);
    gemm_bt<2, 1><<<gg, 256, 0, stream>>>(nullptr, v, WX, bv, nullptr, Vtp, M, DIM, DIM, 1.0f);
    attn_kernel<<<attnGrid, 512, 0, stream>>>(Qhp, Khp, Vtp, X);
    cvt_f32_bf16<<<1024, 256, 0, stream>>>(Wo, WX, nW / 4);
    gemm_bt<0, 0><<<gg, 256, 0, stream>>>(X, nullptr, WX, bo, out, nullptr, M, DIM, DIM, 1.0f);
  }
}

// Round 16
// 204.708 us; speedup vs baseline: 1.1625x; 1.0301x over previous
//
#include <hip/hip_runtime.h>
#include <hip/hip_bf16.h>
#include <stdint.h>

#define NB  4
#define SEQ 2048
#define DIM 1024
#define NH  16
#define DHD 64
#define LOG2E 1.44269504088896340736f

typedef short short8 __attribute__((ext_vector_type(8)));
typedef float f32x4  __attribute__((ext_vector_type(4)));

__device__ __forceinline__ unsigned short f2bf(float f) {
  union { float f; uint32_t u; } x; x.f = f;
  uint32_t u = x.u;
  uint32_t r = (u + 0x7fffu + ((u >> 16) & 1u)) >> 16;  // RNE
  return (unsigned short)r;
}

__device__ __forceinline__ uint32_t cvt_pk_bf16(float lo, float hi) {
  uint32_t r;
  asm("v_cvt_pk_bf16_f32 %0, %1, %2" : "=v"(r) : "v"(lo), "v"(hi));
  return r;
}

// async global->LDS, 16B per lane (dest wave-linear: base + lane*16)
__device__ __forceinline__ void gload16(const void* g, void* l) {
  __builtin_amdgcn_global_load_lds(
      (const __attribute__((address_space(1))) uint32_t*)g,
      (__attribute__((address_space(3))) uint32_t*)l, 16, 0, 0);
}

// ---------------------------------------------------------------- converts
__global__ void cvt_f32_bf16(const float* __restrict__ in,
                             unsigned short* __restrict__ out, int n4) {
  int i = blockIdx.x * blockDim.x + threadIdx.x;
  int stride = gridDim.x * blockDim.x;
  for (int j = i; j < n4; j += stride) {
    float4 v = reinterpret_cast<const float4*>(in)[j];
    ushort4 o;
    o.x = f2bf(v.x); o.y = f2bf(v.y); o.z = f2bf(v.z); o.w = f2bf(v.w);
    reinterpret_cast<ushort4*>(out)[j] = o;
  }
}

__global__ void cvt_w4(const float* __restrict__ w0, const float* __restrict__ w1,
                       const float* __restrict__ w2, const float* __restrict__ w3,
                       unsigned short* __restrict__ o0, unsigned short* __restrict__ o1,
                       unsigned short* __restrict__ o2, unsigned short* __restrict__ o3,
                       int n4) {
  int seg = blockIdx.x >> 8;
  int bid = blockIdx.x & 255;
  const float* in = (seg == 0) ? w0 : (seg == 1) ? w1 : (seg == 2) ? w2 : w3;
  unsigned short* out = (seg == 0) ? o0 : (seg == 1) ? o1 : (seg == 2) ? o2 : o3;
  for (int j = bid * 256 + threadIdx.x; j < n4; j += 65536) {
    float4 v = reinterpret_cast<const float4*>(in)[j];
    ushort4 o;
    o.x = f2bf(v.x); o.y = f2bf(v.y); o.z = f2bf(v.z); o.w = f2bf(v.w);
    reinterpret_cast<ushort4*>(out)[j] = o;
  }
}

// ---------------------------------------------------------------- GEMM (B^T)
// (r15 — unchanged)
template <int MODE, int AF32>
__global__ __launch_bounds__(256, 2) void gemm_bt(
    const unsigned short* __restrict__ A,
    const float* __restrict__ Af,
    const unsigned short* __restrict__ Bm,
    const float* __restrict__ bias,
    float* __restrict__ Cf,
    unsigned short* __restrict__ Cb,
    int M, int N, int K, float scale) {
  __shared__ uint4 smem[4096];

  const int tid  = threadIdx.x;
  const int lane = tid & 63;
  const int wid  = tid >> 6;
  const int cpx  = gridDim.x >> 3;
  const int wg   = (blockIdx.x & 7) * cpx + (blockIdx.x >> 3);
  const int nbn  = N >> 7;
  const int bm   = wg / nbn;
  const int bn   = wg % nbn;
  const int wrow = (wid >> 1) * 64;
  const int wcol = (wid & 1) * 64;

  f32x4 acc[4][4] = {};

  const unsigned short* pa[4];
  const float*          paf[4];
  const unsigned short* pb[4];
  uint4* la[4];
  uint4* lb[4];
#pragma unroll
  for (int i = 0; i < 4; ++i) {
    int c   = tid + (i << 8);
    int row = c >> 3;
    int kc  = (c & 7) ^ (row & 7);
    pa[i]  = A  + (size_t)(bm * 128 + row) * K + kc * 8;
    paf[i] = Af + (size_t)(bm * 128 + row) * K + kc * 8;
    pb[i]  = Bm + (size_t)(bn * 128 + row) * K + kc * 8;
    la[i] = smem + c;
    lb[i] = smem + 2048 + c;
  }

  float4 a32[4][2];
  auto loadA_f32 = [&](int kt) {
#pragma unroll
    for (int i = 0; i < 4; ++i) {
      a32[i][0] = *reinterpret_cast<const float4*>(paf[i] + kt * 64);
      a32[i][1] = *reinterpret_cast<const float4*>(paf[i] + kt * 64 + 4);
    }
  };
  auto writeA_bf16 = [&](int buf) {
#pragma unroll
    for (int i = 0; i < 4; ++i) {
      uint4 w;
      w.x = cvt_pk_bf16(a32[i][0].x, a32[i][0].y);
      w.y = cvt_pk_bf16(a32[i][0].z, a32[i][0].w);
      w.z = cvt_pk_bf16(a32[i][1].x, a32[i][1].y);
      w.w = cvt_pk_bf16(a32[i][1].z, a32[i][1].w);
      *(la[i] + buf * 1024) = w;
    }
  };
  auto stageA_g = [&](int kt, int buf) {
#pragma unroll
    for (int i = 0; i < 4; ++i) gload16(pa[i] + kt * 64, la[i] + buf * 1024);
  };
  auto stageB = [&](int kt, int buf) {
#pragma unroll
    for (int i = 0; i < 4; ++i) gload16(pb[i] + kt * 64, lb[i] + buf * 1024);
  };

  if (AF32) { loadA_f32(0); writeA_bf16(0); }
  else      { stageA_g(0, 0); }
  stageB(0, 0);
  __syncthreads();

  const int NT = K >> 6;
  for (int kt = 0; kt < NT; ++kt) {
    const int cur = kt & 1;
    if (kt + 1 < NT) {
      if (AF32) loadA_f32(kt + 1);
      else      stageA_g(kt + 1, cur ^ 1);
      stageB(kt + 1, cur ^ 1);
    }

#pragma unroll
    for (int s = 0; s < 2; ++s) {
      short8 af[4], bfr[4];
#pragma unroll
      for (int mt = 0; mt < 4; ++mt) {
        int row = wrow + mt * 16 + (lane & 15);
        int ch  = ((s << 2) + (lane >> 4)) ^ (row & 7);
        af[mt]  = __builtin_bit_cast(short8, smem[cur * 1024 + row * 8 + ch]);
      }
#pragma unroll
      for (int nt = 0; nt < 4; ++nt) {
        int row = wcol + nt * 16 + (lane & 15);
        int ch  = ((s << 2) + (lane >> 4)) ^ (row & 7);
        bfr[nt] = __builtin_bit_cast(short8, smem[2048 + cur * 1024 + row * 8 + ch]);
      }
      __builtin_amdgcn_s_setprio(1);
#pragma unroll
      for (int mt = 0; mt < 4; ++mt)
#pragma unroll
        for (int nt = 0; nt < 4; ++nt)
          acc[mt][nt] = __builtin_amdgcn_mfma_f32_16x16x32_bf16(af[mt], bfr[nt], acc[mt][nt], 0, 0, 0);
      __builtin_amdgcn_s_setprio(0);
    }

    if (AF32 && kt + 1 < NT) writeA_bf16(cur ^ 1);
    __syncthreads();
  }

  if (MODE == 1) {
    unsigned short* cb = (unsigned short*)smem;  // [128][128] bf16
#pragma unroll
    for (int nt = 0; nt < 4; ++nt) {
      int tcol = wcol + nt * 16 + (lane & 15);
      float bv = bias[bn * 128 + tcol];
#pragma unroll
      for (int mt = 0; mt < 4; ++mt)
#pragma unroll
        for (int r = 0; r < 4; ++r) {
          int trow = wrow + mt * 16 + (lane >> 4) * 4 + r;
          cb[trow * 128 + tcol] = f2bf((acc[mt][nt][r] + bv) * scale);
        }
    }
    __syncthreads();
#pragma unroll
    for (int it = 0; it < 8; ++it) {
      int idx = tid + it * 256;
      int row = idx >> 4, seg = idx & 15;
      uint4 val = ((uint4*)cb)[idx];
      int gcol = bn * 128 + seg * 8;
      int h = gcol >> 6, dh = gcol & 63;
      int grow = bm * 128 + row;
      int b = grow >> 11, lq = grow & 2047;
      *reinterpret_cast<uint4*>(Cb + ((size_t)((b << 4) + h) * SEQ + lq) * DHD + dh) = val;
    }
  } else {
    const int rbase = bm * 128 + wrow + (lane >> 4) * 4;
    const int cbase = bn * 128 + wcol + (lane & 15);
#pragma unroll
    for (int nt = 0; nt < 4; ++nt) {
      int col  = cbase + nt * 16;
      float bv = bias[col];
#pragma unroll
      for (int mt = 0; mt < 4; ++mt) {
        if (MODE == 2) {
          int h = col >> 6, dh = col & 63;
          int row0 = rbase + mt * 16;
          int b = row0 >> 11, lq = row0 & 2047;
          uint2 pk;
          pk.x = cvt_pk_bf16((acc[mt][nt][0] + bv) * scale, (acc[mt][nt][1] + bv) * scale);
          pk.y = cvt_pk_bf16((acc[mt][nt][2] + bv) * scale, (acc[mt][nt][3] + bv) * scale);
          *reinterpret_cast<uint2*>(Cb + ((size_t)((b << 4) + h) * DHD + dh) * SEQ + lq) = pk;
        } else {
#pragma unroll
          for (int r = 0; r < 4; ++r) {
            int row = rbase + mt * 16 + r;
            Cf[(size_t)row * N + col] = acc[mt][nt][r] + bv;
          }
        }
      }
    }
  }
}

// ---------------------------------------------------------------- attention
// r11 structure, K-loop unrolled x2 with STATIC buffer parity: tile body is
// a lambda called with literal 0/1 so every LDS address folds to base+imm
// (cuts per-tile VALU address recomputation — the 58%-VALUBusy excess).
// Staging uses bump-pointers (no per-tile 64-bit mul-add).
__global__ __launch_bounds__(512, 4) void attn_kernel(
    const unsigned short* __restrict__ Qh,
    const unsigned short* __restrict__ Kh,
    const unsigned short* __restrict__ Vt,
    unsigned short* __restrict__ O) {
  __shared__ uint4 Kls[2][512];
  __shared__ uint4 Vls[2][512];
  __shared__ uint4 Pls[8][32 * 9];

  const int tid  = threadIdx.x;
  const int lane = tid & 63;
  const int wid  = tid >> 6;
  const int wg   = (blockIdx.x & 7) * 64 + (blockIdx.x >> 3);
  const int bh   = wg >> 3;
  const int qt   = wg & 7;
  const int qloc = lane & 15;
  const int grp  = lane >> 4;
  const int q7   = qloc & 7;

  const unsigned short* Qb = Qh + (size_t)bh * SEQ * DHD;
  const unsigned short* Kb = Kh + (size_t)bh * SEQ * DHD;
  const unsigned short* Vb = Vt + (size_t)bh * DHD * SEQ;

  const int srow = tid >> 3;
  const int skc  = (tid & 7) ^ (srow & 7);
  const unsigned short* pkP = Kb + (size_t)srow * DHD + skc * 8;
  const unsigned short* pvP = Vb + (size_t)srow * SEQ + skc * 8;
  auto stageNext = [&](int buf) {   // stages the next tile, bumps pointers
    gload16(pkP, &Kls[buf][tid]);
    gload16(pvP, &Vls[buf][tid]);
    pkP += 64 * DHD;
    pvP += 64;
  };

  stageNext(0);  // tile 0

  short8 qf[2][2];
#pragma unroll
  for (int qb = 0; qb < 2; ++qb) {
    int qrow = qt * 256 + wid * 32 + qb * 16 + qloc;
#pragma unroll
    for (int s = 0; s < 2; ++s)
      qf[qb][s] = *reinterpret_cast<const short8*>(Qb + (size_t)qrow * DHD + s * 32 + grp * 8);
  }

  const short8 ones = {0x3F80, 0x3F80, 0x3F80, 0x3F80, 0x3F80, 0x3F80, 0x3F80, 0x3F80};
  char* pwb = (char*)&Pls[wid][0];

  __syncthreads();

  float logbias = 0.f;
  f32x4 lsum[2] = {};
  f32x4 acc_o[4][2] = {};

  auto tile_body = [&](int cur) {   // called with literal 0/1 -> static LDS addrs
    f32x4 sc[4][2];
    __builtin_amdgcn_s_setprio(1);
#pragma unroll
    for (int j = 0; j < 4; ++j) {
      short8 kf[2];
#pragma unroll
      for (int s = 0; s < 2; ++s) {
        int krow = j * 16 + qloc;
        int ch   = ((s << 2) + grp) ^ q7;
        kf[s] = __builtin_bit_cast(short8, Kls[cur][krow * 8 + ch]);
      }
#pragma unroll
      for (int qb = 0; qb < 2; ++qb) {
        f32x4 a = {logbias, logbias, logbias, logbias};
        a = __builtin_amdgcn_mfma_f32_16x16x32_bf16(kf[0], qf[qb][0], a, 0, 0, 0);
        a = __builtin_amdgcn_mfma_f32_16x16x32_bf16(kf[1], qf[qb][1], a, 0, 0, 0);
        sc[j][qb] = a;
      }
    }
    __builtin_amdgcn_s_setprio(0);

#pragma unroll
    for (int j = 0; j < 4; ++j)
#pragma unroll
      for (int qb = 0; qb < 2; ++qb) {
        float p0 = exp2f(sc[j][qb][0]);
        float p1 = exp2f(sc[j][qb][1]);
        float p2 = exp2f(sc[j][qb][2]);
        float p3 = exp2f(sc[j][qb][3]);
        uint2 w;
        w.x = cvt_pk_bf16(p0, p1);
        w.y = cvt_pk_bf16(p2, p3);
        *(uint2*)(pwb + (qb * 16 + qloc) * 144 + j * 32 + grp * 8) = w;
      }

    short8 pf[2][2];
#pragma unroll
    for (int qb = 0; qb < 2; ++qb)
#pragma unroll
      for (int t = 0; t < 2; ++t)
        pf[qb][t] = *(const short8*)(pwb + (qb * 16 + qloc) * 144 + t * 64 + grp * 16);

    __builtin_amdgcn_s_setprio(1);
#pragma unroll
    for (int db = 0; db < 4; ++db) {
      short8 vf[2];
#pragma unroll
      for (int t = 0; t < 2; ++t) {
        int vrow = db * 16 + qloc;
        int ch   = ((t << 2) + grp) ^ q7;
        vf[t] = __builtin_bit_cast(short8, Vls[cur][vrow * 8 + ch]);
      }
#pragma unroll
      for (int qb = 0; qb < 2; ++qb) {
        acc_o[db][qb] = __builtin_amdgcn_mfma_f32_16x16x32_bf16(vf[0], pf[qb][0], acc_o[db][qb], 0, 0, 0);
        acc_o[db][qb] = __builtin_amdgcn_mfma_f32_16x16x32_bf16(vf[1], pf[qb][1], acc_o[db][qb], 0, 0, 0);
      }
    }
#pragma unroll
    for (int qb = 0; qb < 2; ++qb) {
      lsum[qb] = __builtin_amdgcn_mfma_f32_16x16x32_bf16(ones, pf[qb][0], lsum[qb], 0, 0, 0);
      lsum[qb] = __builtin_amdgcn_mfma_f32_16x16x32_bf16(ones, pf[qb][1], lsum[qb], 0, 0, 0);
    }
    __builtin_amdgcn_s_setprio(0);

    if (__any(fmaxf(lsum[0][0], lsum[1][0]) > 7.9e28f)) {
      const float ds = 5.421010862e-20f;  // 2^-64
      logbias -= 64.f;
#pragma unroll
      for (int db = 0; db < 4; ++db)
#pragma unroll
        for (int qb = 0; qb < 2; ++qb)
#pragma unroll
          for (int r = 0; r < 4; ++r) acc_o[db][qb][r] *= ds;
#pragma unroll
      for (int qb = 0; qb < 2; ++qb)
#pragma unroll
        for (int r = 0; r < 4; ++r) lsum[qb][r] *= ds;
    }
  };

  const int NH2 = (SEQ / 64) / 2;  // 16 unrolled pairs
#pragma unroll 1
  for (int it = 0; it < NH2; ++it) {
    stageNext(1);                      // tile 2*it+1 -> buf1
    tile_body(0);                      // tile 2*it   (buf0)
    __syncthreads();
    if (it + 1 < NH2) stageNext(0);    // tile 2*it+2 -> buf0
    tile_body(1);                      // tile 2*it+1 (buf1)
    __syncthreads();
  }

  const float inv0 = 1.0f / lsum[0][0];
  const float inv1 = 1.0f / lsum[1][0];
#pragma unroll
  for (int db = 0; db < 4; ++db)
#pragma unroll
    for (int qb = 0; qb < 2; ++qb) {
      float inv = qb ? inv1 : inv0;
      uint2 w;
      w.x = cvt_pk_bf16(acc_o[db][qb][0] * inv, acc_o[db][qb][1] * inv);
      w.y = cvt_pk_bf16(acc_o[db][qb][2] * inv, acc_o[db][qb][3] * inv);
      *(uint2*)(pwb + (qb * 16 + qloc) * 144 + db * 32 + grp * 8) = w;
    }
  const int b = bh >> 4, h = bh & 15;
#pragma unroll
  for (int pass = 0; pass < 4; ++pass) {
    int idx = pass * 64 + lane;
    int row = idx >> 3;
    int ck  = idx & 7;
    uint4 val = *(const uint4*)(pwb + row * 144 + ck * 16);
    int rowg  = qt * 256 + wid * 32 + row;
    *reinterpret_cast<uint4*>(O + ((size_t)(b * SEQ + rowg)) * DIM + (h << 6) + ck * 8) = val;
  }
}

// ---------------------------------------------------------------- launch
extern "C" void kernel_launch(void* const* d_in, const int* in_sizes, int n_in,
                              void* d_out, int out_size, void* d_ws, size_t ws_size,
                              hipStream_t stream) {
  (void)in_sizes; (void)n_in; (void)out_size;
  const float* q  = (const float*)d_in[0];
  const float* k  = (const float*)d_in[1];
  const float* v  = (const float*)d_in[2];
  const float* Wq = (const float*)d_in[3];
  const float* bq = (const float*)d_in[4];
  const float* Wk = (const float*)d_in[5];
  const float* bk = (const float*)d_in[6];
  const float* Wv = (const float*)d_in[7];
  const float* bv = (const float*)d_in[8];
  const float* Wo = (const float*)d_in[9];
  const float* bo = (const float*)d_in[10];
  float* out = (float*)d_out;

  char* ws = (char*)d_ws;
  const size_t MB = 1024 * 1024;
  const int nW = DIM * DIM;
  const int M  = NB * SEQ;
  dim3 gg((M / 128) * (DIM / 128));            // 512 blocks
  const int attnGrid = NB * NH * (SEQ / 256);  // 512 blocks

  if (ws_size >= 73 * MB) {
    unsigned short* X   = (unsigned short*)(ws + 0);
    unsigned short* WXq = (unsigned short*)(ws + 16 * MB);
    unsigned short* WXk = (unsigned short*)(ws + 18 * MB);
    unsigned short* WXv = (unsigned short*)(ws + 20 * MB);
    unsigned short* WXo = (unsigned short*)(ws + 22 * MB);
    unsigned short* Qhp = (unsigned short*)(ws + 24 * MB);
    unsigned short* Khp = (unsigned short*)(ws + 40 * MB);
    unsigned short* Vtp = (unsigned short*)(ws + 56 * MB);

    cvt_w4<<<1024, 256, 0, stream>>>(Wq, Wk, Wv, Wo, WXq, WXk, WXv, WXo, nW / 4);
    gemm_bt<1, 1><<<gg, 256, 0, stream>>>(nullptr, q, WXq, bq, nullptr, Qhp, M, DIM, DIM, 0.125f * LOG2E);
    gemm_bt<1, 1><<<gg, 256, 0, stream>>>(nullptr, k, WXk, bk, nullptr, Khp, M, DIM, DIM, 1.0f);
    gemm_bt<2, 1><<<gg, 256, 0, stream>>>(nullptr, v, WXv, bv, nullptr, Vtp, M, DIM, DIM, 1.0f);
    attn_kernel<<<attnGrid, 512, 0, stream>>>(Qhp, Khp, Vtp, X);
    gemm_bt<0, 0><<<gg, 256, 0, stream>>>(X, nullptr, WXo, bo, out, nullptr, M, DIM, DIM, 1.0f);
  } else {
    unsigned short* X   = (unsigned short*)(ws + 0);
    unsigned short* WX  = (unsigned short*)(ws + 16 * MB);
    unsigned short* Qhp = (unsigned short*)(ws + 18 * MB);
    unsigned short* Khp = (unsigned short*)(ws + 34 * MB);
    unsigned short* Vtp = (unsigned short*)(ws + 50 * MB);

    cvt_f32_bf16<<<1024, 256, 0, stream>>>(Wq, WX, nW / 4);
    gemm_bt<1, 1><<<gg, 256, 0, stream>>>(nullptr, q, WX, bq, nullptr, Qhp, M, DIM, DIM, 0.125f * LOG2E);
    cvt_f32_bf16<<<1024, 256, 0, stream>>>(Wk, WX, nW / 4);
    gemm_bt<1, 1><<<gg, 256, 0, stream>>>(nullptr, k, WX, bk, nullptr, Khp, M, DIM, DIM, 1.0f);
    cvt_f32_bf16<<<1024, 256, 0, stream>>>(Wv, WX, nW / 4);
    gemm_bt<2, 1><<<gg, 256, 0, stream>>>(nullptr, v, WX, bv, nullptr, Vtp, M, DIM, DIM, 1.0f);
    attn_kernel<<<attnGrid, 512, 0, stream>>>(Qhp, Khp, Vtp, X);
    cvt_f32_bf16<<<1024, 256, 0, stream>>>(Wo, WX, nW / 4);
    gemm_bt<0, 0><<<gg, 256, 0, stream>>>(X, nullptr, WX, bo, out, nullptr, M, DIM, DIM, 1.0f);
  }
}

// Round 17
// 204.694 us; speedup vs baseline: 1.1626x; 1.0001x over previous
//
#include <hip/hip_runtime.h>
#include <hip/hip_bf16.h>
#include <stdint.h>

#define NB  4
#define SEQ 2048
#define DIM 1024
#define NH  16
#define DHD 64
#define LOG2E 1.44269504088896340736f

typedef short short8 __attribute__((ext_vector_type(8)));
typedef float f32x4  __attribute__((ext_vector_type(4)));

__device__ __forceinline__ unsigned short f2bf(float f) {
  union { float f; uint32_t u; } x; x.f = f;
  uint32_t u = x.u;
  uint32_t r = (u + 0x7fffu + ((u >> 16) & 1u)) >> 16;  // RNE
  return (unsigned short)r;
}

__device__ __forceinline__ uint32_t cvt_pk_bf16(float lo, float hi) {
  uint32_t r;
  asm("v_cvt_pk_bf16_f32 %0, %1, %2" : "=v"(r) : "v"(lo), "v"(hi));
  return r;
}

// async global->LDS, 16B per lane (dest wave-linear: base + lane*16)
__device__ __forceinline__ void gload16(const void* g, void* l) {
  __builtin_amdgcn_global_load_lds(
      (const __attribute__((address_space(1))) uint32_t*)g,
      (__attribute__((address_space(3))) uint32_t*)l, 16, 0, 0);
}

// ---------------------------------------------------------------- converts
__global__ void cvt_f32_bf16(const float* __restrict__ in,
                             unsigned short* __restrict__ out, int n4) {
  int i = blockIdx.x * blockDim.x + threadIdx.x;
  int stride = gridDim.x * blockDim.x;
  for (int j = i; j < n4; j += stride) {
    float4 v = reinterpret_cast<const float4*>(in)[j];
    ushort4 o;
    o.x = f2bf(v.x); o.y = f2bf(v.y); o.z = f2bf(v.z); o.w = f2bf(v.w);
    reinterpret_cast<ushort4*>(out)[j] = o;
  }
}

__global__ void cvt_w4(const float* __restrict__ w0, const float* __restrict__ w1,
                       const float* __restrict__ w2, const float* __restrict__ w3,
                       unsigned short* __restrict__ o0, unsigned short* __restrict__ o1,
                       unsigned short* __restrict__ o2, unsigned short* __restrict__ o3,
                       int n4) {
  int seg = blockIdx.x >> 8;
  int bid = blockIdx.x & 255;
  const float* in = (seg == 0) ? w0 : (seg == 1) ? w1 : (seg == 2) ? w2 : w3;
  unsigned short* out = (seg == 0) ? o0 : (seg == 1) ? o1 : (seg == 2) ? o2 : o3;
  for (int j = bid * 256 + threadIdx.x; j < n4; j += 65536) {
    float4 v = reinterpret_cast<const float4*>(in)[j];
    ushort4 o;
    o.x = f2bf(v.x); o.y = f2bf(v.y); o.z = f2bf(v.z); o.w = f2bf(v.w);
    reinterpret_cast<ushort4*>(out)[j] = o;
  }
}

// ---------------------------------------------------------------- GEMM (B^T)
// r15 structure + K-loop unroll x2 with STATIC buffer parity (r16-proven
// pattern): tile body called with literal 0/1 so LDS addrs fold to base+imm;
// staging pointers are bump-pointers. Requires NT even (all call sites K=1024).
template <int MODE, int AF32>
__global__ __launch_bounds__(256, 2) void gemm_bt(
    const unsigned short* __restrict__ A,
    const float* __restrict__ Af,
    const unsigned short* __restrict__ Bm,
    const float* __restrict__ bias,
    float* __restrict__ Cf,
    unsigned short* __restrict__ Cb,
    int M, int N, int K, float scale) {
  __shared__ uint4 smem[4096];

  const int tid  = threadIdx.x;
  const int lane = tid & 63;
  const int wid  = tid >> 6;
  const int cpx  = gridDim.x >> 3;
  const int wg   = (blockIdx.x & 7) * cpx + (blockIdx.x >> 3);
  const int nbn  = N >> 7;
  const int bm   = wg / nbn;
  const int bn   = wg % nbn;
  const int wrow = (wid >> 1) * 64;
  const int wcol = (wid & 1) * 64;

  f32x4 acc[4][4] = {};

  const unsigned short* pa[4];
  const float*          paf[4];
  const unsigned short* pb[4];
  uint4* la[4];
  uint4* lb[4];
#pragma unroll
  for (int i = 0; i < 4; ++i) {
    int c   = tid + (i << 8);
    int row = c >> 3;
    int kc  = (c & 7) ^ (row & 7);
    pa[i]  = A  + (size_t)(bm * 128 + row) * K + kc * 8;
    paf[i] = Af + (size_t)(bm * 128 + row) * K + kc * 8;
    pb[i]  = Bm + (size_t)(bn * 128 + row) * K + kc * 8;
    la[i] = smem + c;
    lb[i] = smem + 2048 + c;
  }

  float4 a32[4][2];
  auto loadA_f32 = [&]() {   // loads next A tile (fp32) and bumps
#pragma unroll
    for (int i = 0; i < 4; ++i) {
      a32[i][0] = *reinterpret_cast<const float4*>(paf[i]);
      a32[i][1] = *reinterpret_cast<const float4*>(paf[i] + 4);
      paf[i] += 64;
    }
  };
  auto writeA_bf16 = [&](int buf) {
#pragma unroll
    for (int i = 0; i < 4; ++i) {
      uint4 w;
      w.x = cvt_pk_bf16(a32[i][0].x, a32[i][0].y);
      w.y = cvt_pk_bf16(a32[i][0].z, a32[i][0].w);
      w.z = cvt_pk_bf16(a32[i][1].x, a32[i][1].y);
      w.w = cvt_pk_bf16(a32[i][1].z, a32[i][1].w);
      *(la[i] + buf * 1024) = w;
    }
  };
  auto stageA_g = [&](int buf) {   // stages next A tile (bf16) and bumps
#pragma unroll
    for (int i = 0; i < 4; ++i) { gload16(pa[i], la[i] + buf * 1024); pa[i] += 64; }
  };
  auto stageB = [&](int buf) {     // stages next B tile and bumps
#pragma unroll
    for (int i = 0; i < 4; ++i) { gload16(pb[i], lb[i] + buf * 1024); pb[i] += 64; }
  };

  auto body = [&](int cur) {       // called with literal 0/1
#pragma unroll
    for (int s = 0; s < 2; ++s) {
      short8 af[4], bfr[4];
#pragma unroll
      for (int mt = 0; mt < 4; ++mt) {
        int row = wrow + mt * 16 + (lane & 15);
        int ch  = ((s << 2) + (lane >> 4)) ^ (row & 7);
        af[mt]  = __builtin_bit_cast(short8, smem[cur * 1024 + row * 8 + ch]);
      }
#pragma unroll
      for (int nt = 0; nt < 4; ++nt) {
        int row = wcol + nt * 16 + (lane & 15);
        int ch  = ((s << 2) + (lane >> 4)) ^ (row & 7);
        bfr[nt] = __builtin_bit_cast(short8, smem[2048 + cur * 1024 + row * 8 + ch]);
      }
      __builtin_amdgcn_s_setprio(1);
#pragma unroll
      for (int mt = 0; mt < 4; ++mt)
#pragma unroll
        for (int nt = 0; nt < 4; ++nt)
          acc[mt][nt] = __builtin_amdgcn_mfma_f32_16x16x32_bf16(af[mt], bfr[nt], acc[mt][nt], 0, 0, 0);
      __builtin_amdgcn_s_setprio(0);
    }
  };

  // prologue: tile 0 -> buf0
  if (AF32) { loadA_f32(); writeA_bf16(0); }
  else      { stageA_g(0); }
  stageB(0);
  __syncthreads();

  const int NTh = (K >> 6) >> 1;  // pairs (K=1024 -> 8)
#pragma unroll 1
  for (int it = 0; it < NTh; ++it) {
    // tile 2it (buf0); prefetch 2it+1 -> buf1 (always exists)
    if (AF32) loadA_f32(); else stageA_g(1);
    stageB(1);
    body(0);
    if (AF32) writeA_bf16(1);
    __syncthreads();
    // tile 2it+1 (buf1); prefetch 2it+2 -> buf0 (if exists)
    if (it + 1 < NTh) {
      if (AF32) loadA_f32(); else stageA_g(0);
      stageB(0);
    }
    body(1);
    if (AF32 && it + 1 < NTh) writeA_bf16(0);
    __syncthreads();
  }

  if (MODE == 1) {
    unsigned short* cb = (unsigned short*)smem;  // [128][128] bf16
#pragma unroll
    for (int nt = 0; nt < 4; ++nt) {
      int tcol = wcol + nt * 16 + (lane & 15);
      float bv = bias[bn * 128 + tcol];
#pragma unroll
      for (int mt = 0; mt < 4; ++mt)
#pragma unroll
        for (int r = 0; r < 4; ++r) {
          int trow = wrow + mt * 16 + (lane >> 4) * 4 + r;
          cb[trow * 128 + tcol] = f2bf((acc[mt][nt][r] + bv) * scale);
        }
    }
    __syncthreads();
#pragma unroll
    for (int it = 0; it < 8; ++it) {
      int idx = tid + it * 256;
      int row = idx >> 4, seg = idx & 15;
      uint4 val = ((uint4*)cb)[idx];
      int gcol = bn * 128 + seg * 8;
      int h = gcol >> 6, dh = gcol & 63;
      int grow = bm * 128 + row;
      int b = grow >> 11, lq = grow & 2047;
      *reinterpret_cast<uint4*>(Cb + ((size_t)((b << 4) + h) * SEQ + lq) * DHD + dh) = val;
    }
  } else {
    const int rbase = bm * 128 + wrow + (lane >> 4) * 4;
    const int cbase = bn * 128 + wcol + (lane & 15);
#pragma unroll
    for (int nt = 0; nt < 4; ++nt) {
      int col  = cbase + nt * 16;
      float bv = bias[col];
#pragma unroll
      for (int mt = 0; mt < 4; ++mt) {
        if (MODE == 2) {
          int h = col >> 6, dh = col & 63;
          int row0 = rbase + mt * 16;
          int b = row0 >> 11, lq = row0 & 2047;
          uint2 pk;
          pk.x = cvt_pk_bf16((acc[mt][nt][0] + bv) * scale, (acc[mt][nt][1] + bv) * scale);
          pk.y = cvt_pk_bf16((acc[mt][nt][2] + bv) * scale, (acc[mt][nt][3] + bv) * scale);
          *reinterpret_cast<uint2*>(Cb + ((size_t)((b << 4) + h) * DHD + dh) * SEQ + lq) = pk;
        } else {
#pragma unroll
          for (int r = 0; r < 4; ++r) {
            int row = rbase + mt * 16 + r;
            Cf[(size_t)row * N + col] = acc[mt][nt][r] + bv;
          }
        }
      }
    }
  }
}

// ---------------------------------------------------------------- attention
// r16 structure + persistent lb4 broadcast register as the QK^T MFMA C-operand
// (removes ~32 v_mov/tile of logbias C-init; MFMA D and C are separate fields).
__global__ __launch_bounds__(512, 4) void attn_kernel(
    const unsigned short* __restrict__ Qh,
    const unsigned short* __restrict__ Kh,
    const unsigned short* __restrict__ Vt,
    unsigned short* __restrict__ O) {
  __shared__ uint4 Kls[2][512];
  __shared__ uint4 Vls[2][512];
  __shared__ uint4 Pls[8][32 * 9];

  const int tid  = threadIdx.x;
  const int lane = tid & 63;
  const int wid  = tid >> 6;
  const int wg   = (blockIdx.x & 7) * 64 + (blockIdx.x >> 3);
  const int bh   = wg >> 3;
  const int qt   = wg & 7;
  const int qloc = lane & 15;
  const int grp  = lane >> 4;
  const int q7   = qloc & 7;

  const unsigned short* Qb = Qh + (size_t)bh * SEQ * DHD;
  const unsigned short* Kb = Kh + (size_t)bh * SEQ * DHD;
  const unsigned short* Vb = Vt + (size_t)bh * DHD * SEQ;

  const int srow = tid >> 3;
  const int skc  = (tid & 7) ^ (srow & 7);
  const unsigned short* pkP = Kb + (size_t)srow * DHD + skc * 8;
  const unsigned short* pvP = Vb + (size_t)srow * SEQ + skc * 8;
  auto stageNext = [&](int buf) {
    gload16(pkP, &Kls[buf][tid]);
    gload16(pvP, &Vls[buf][tid]);
    pkP += 64 * DHD;
    pvP += 64;
  };

  stageNext(0);  // tile 0

  short8 qf[2][2];
#pragma unroll
  for (int qb = 0; qb < 2; ++qb) {
    int qrow = qt * 256 + wid * 32 + qb * 16 + qloc;
#pragma unroll
    for (int s = 0; s < 2; ++s)
      qf[qb][s] = *reinterpret_cast<const short8*>(Qb + (size_t)qrow * DHD + s * 32 + grp * 8);
  }

  const short8 ones = {0x3F80, 0x3F80, 0x3F80, 0x3F80, 0x3F80, 0x3F80, 0x3F80, 0x3F80};
  char* pwb = (char*)&Pls[wid][0];

  __syncthreads();

  f32x4 lb4 = {0.f, 0.f, 0.f, 0.f};   // logbias broadcast, C-operand for QK^T
  f32x4 lsum[2] = {};
  f32x4 acc_o[4][2] = {};

  auto tile_body = [&](int cur) {   // literal 0/1 -> static LDS addrs
    f32x4 sc[4][2];
    __builtin_amdgcn_s_setprio(1);
#pragma unroll
    for (int j = 0; j < 4; ++j) {
      short8 kf[2];
#pragma unroll
      for (int s = 0; s < 2; ++s) {
        int krow = j * 16 + qloc;
        int ch   = ((s << 2) + grp) ^ q7;
        kf[s] = __builtin_bit_cast(short8, Kls[cur][krow * 8 + ch]);
      }
#pragma unroll
      for (int qb = 0; qb < 2; ++qb) {
        f32x4 a = __builtin_amdgcn_mfma_f32_16x16x32_bf16(kf[0], qf[qb][0], lb4, 0, 0, 0);
        a = __builtin_amdgcn_mfma_f32_16x16x32_bf16(kf[1], qf[qb][1], a, 0, 0, 0);
        sc[j][qb] = a;
      }
    }
    __builtin_amdgcn_s_setprio(0);

#pragma unroll
    for (int j = 0; j < 4; ++j)
#pragma unroll
      for (int qb = 0; qb < 2; ++qb) {
        float p0 = exp2f(sc[j][qb][0]);
        float p1 = exp2f(sc[j][qb][1]);
        float p2 = exp2f(sc[j][qb][2]);
        float p3 = exp2f(sc[j][qb][3]);
        uint2 w;
        w.x = cvt_pk_bf16(p0, p1);
        w.y = cvt_pk_bf16(p2, p3);
        *(uint2*)(pwb + (qb * 16 + qloc) * 144 + j * 32 + grp * 8) = w;
      }

    short8 pf[2][2];
#pragma unroll
    for (int qb = 0; qb < 2; ++qb)
#pragma unroll
      for (int t = 0; t < 2; ++t)
        pf[qb][t] = *(const short8*)(pwb + (qb * 16 + qloc) * 144 + t * 64 + grp * 16);

    __builtin_amdgcn_s_setprio(1);
#pragma unroll
    for (int db = 0; db < 4; ++db) {
      short8 vf[2];
#pragma unroll
      for (int t = 0; t < 2; ++t) {
        int vrow = db * 16 + qloc;
        int ch   = ((t << 2) + grp) ^ q7;
        vf[t] = __builtin_bit_cast(short8, Vls[cur][vrow * 8 + ch]);
      }
#pragma unroll
      for (int qb = 0; qb < 2; ++qb) {
        acc_o[db][qb] = __builtin_amdgcn_mfma_f32_16x16x32_bf16(vf[0], pf[qb][0], acc_o[db][qb], 0, 0, 0);
        acc_o[db][qb] = __builtin_amdgcn_mfma_f32_16x16x32_bf16(vf[1], pf[qb][1], acc_o[db][qb], 0, 0, 0);
      }
    }
#pragma unroll
    for (int qb = 0; qb < 2; ++qb) {
      lsum[qb] = __builtin_amdgcn_mfma_f32_16x16x32_bf16(ones, pf[qb][0], lsum[qb], 0, 0, 0);
      lsum[qb] = __builtin_amdgcn_mfma_f32_16x16x32_bf16(ones, pf[qb][1], lsum[qb], 0, 0, 0);
    }
    __builtin_amdgcn_s_setprio(0);

    if (__any(fmaxf(lsum[0][0], lsum[1][0]) > 7.9e28f)) {
      const float ds = 5.421010862e-20f;  // 2^-64
#pragma unroll
      for (int r = 0; r < 4; ++r) lb4[r] -= 64.f;
#pragma unroll
      for (int db = 0; db < 4; ++db)
#pragma unroll
        for (int qb = 0; qb < 2; ++qb)
#pragma unroll
          for (int r = 0; r < 4; ++r) acc_o[db][qb][r] *= ds;
#pragma unroll
      for (int qb = 0; qb < 2; ++qb)
#pragma unroll
        for (int r = 0; r < 4; ++r) lsum[qb][r] *= ds;
    }
  };

  const int NH2 = (SEQ / 64) / 2;  // 16 unrolled pairs
#pragma unroll 1
  for (int it = 0; it < NH2; ++it) {
    stageNext(1);                      // tile 2*it+1 -> buf1
    tile_body(0);                      // tile 2*it   (buf0)
    __syncthreads();
    if (it + 1 < NH2) stageNext(0);    // tile 2*it+2 -> buf0
    tile_body(1);                      // tile 2*it+1 (buf1)
    __syncthreads();
  }

  const float inv0 = 1.0f / lsum[0][0];
  const float inv1 = 1.0f / lsum[1][0];
#pragma unroll
  for (int db = 0; db < 4; ++db)
#pragma unroll
    for (int qb = 0; qb < 2; ++qb) {
      float inv = qb ? inv1 : inv0;
      uint2 w;
      w.x = cvt_pk_bf16(acc_o[db][qb][0] * inv, acc_o[db][qb][1] * inv);
      w.y = cvt_pk_bf16(acc_o[db][qb][2] * inv, acc_o[db][qb][3] * inv);
      *(uint2*)(pwb + (qb * 16 + qloc) * 144 + db * 32 + grp * 8) = w;
    }
  const int b = bh >> 4, h = bh & 15;
#pragma unroll
  for (int pass = 0; pass < 4; ++pass) {
    int idx = pass * 64 + lane;
    int row = idx >> 3;
    int ck  = idx & 7;
    uint4 val = *(const uint4*)(pwb + row * 144 + ck * 16);
    int rowg  = qt * 256 + wid * 32 + row;
    *reinterpret_cast<uint4*>(O + ((size_t)(b * SEQ + rowg)) * DIM + (h << 6) + ck * 8) = val;
  }
}

// ---------------------------------------------------------------- launch
extern "C" void kernel_launch(void* const* d_in, const int* in_sizes, int n_in,
                              void* d_out, int out_size, void* d_ws, size_t ws_size,
                              hipStream_t stream) {
  (void)in_sizes; (void)n_in; (void)out_size;
  const float* q  = (const float*)d_in[0];
  const float* k  = (const float*)d_in[1];
  const float* v  = (const float*)d_in[2];
  const float* Wq = (const float*)d_in[3];
  const float* bq = (const float*)d_in[4];
  const float* Wk = (const float*)d_in[5];
  const float* bk = (const float*)d_in[6];
  const float* Wv = (const float*)d_in[7];
  const float* bv = (const float*)d_in[8];
  const float* Wo = (const float*)d_in[9];
  const float* bo = (const float*)d_in[10];
  float* out = (float*)d_out;

  char* ws = (char*)d_ws;
  const size_t MB = 1024 * 1024;
  const int nW = DIM * DIM;
  const int M  = NB * SEQ;
  dim3 gg((M / 128) * (DIM / 128));            // 512 blocks
  const int attnGrid = NB * NH * (SEQ / 256);  // 512 blocks

  if (ws_size >= 73 * MB) {
    unsigned short* X   = (unsigned short*)(ws + 0);
    unsigned short* WXq = (unsigned short*)(ws + 16 * MB);
    unsigned short* WXk = (unsigned short*)(ws + 18 * MB);
    unsigned short* WXv = (unsigned short*)(ws + 20 * MB);
    unsigned short* WXo = (unsigned short*)(ws + 22 * MB);
    unsigned short* Qhp = (unsigned short*)(ws + 24 * MB);
    unsigned short* Khp = (unsigned short*)(ws + 40 * MB);
    unsigned short* Vtp = (unsigned short*)(ws + 56 * MB);

    cvt_w4<<<1024, 256, 0, stream>>>(Wq, Wk, Wv, Wo, WXq, WXk, WXv, WXo, nW / 4);
    gemm_bt<1, 1><<<gg, 256, 0, stream>>>(nullptr, q, WXq, bq, nullptr, Qhp, M, DIM, DIM, 0.125f * LOG2E);
    gemm_bt<1, 1><<<gg, 256, 0, stream>>>(nullptr, k, WXk, bk, nullptr, Khp, M, DIM, DIM, 1.0f);
    gemm_bt<2, 1><<<gg, 256, 0, stream>>>(nullptr, v, WXv, bv, nullptr, Vtp, M, DIM, DIM, 1.0f);
    attn_kernel<<<attnGrid, 512, 0, stream>>>(Qhp, Khp, Vtp, X);
    gemm_bt<0, 0><<<gg, 256, 0, stream>>>(X, nullptr, WXo, bo, out, nullptr, M, DIM, DIM, 1.0f);
  } else {
    unsigned short* X   = (unsigned short*)(ws + 0);
    unsigned short* WX  = (unsigned short*)(ws + 16 * MB);
    unsigned short* Qhp = (unsigned short*)(ws + 18 * MB);
    unsigned short* Khp = (unsigned short*)(ws + 34 * MB);
    unsigned short* Vtp = (unsigned short*)(ws + 50 * MB);

    cvt_f32_bf16<<<1024, 256, 0, stream>>>(Wq, WX, nW / 4);
    gemm_bt<1, 1><<<gg, 256, 0, stream>>>(nullptr, q, WX, bq, nullptr, Qhp, M, DIM, DIM, 0.125f * LOG2E);
    cvt_f32_bf16<<<1024, 256, 0, stream>>>(Wk, WX, nW / 4);
    gemm_bt<1, 1><<<gg, 256, 0, stream>>>(nullptr, k, WX, bk, nullptr, Khp, M, DIM, DIM, 1.0f);
    cvt_f32_bf16<<<1024, 256, 0, stream>>>(Wv, WX, nW / 4);
    gemm_bt<2, 1><<<gg, 256, 0, stream>>>(nullptr, v, WX, bv, nullptr, Vtp, M, DIM, DIM, 1.0f);
    attn_kernel<<<attnGrid, 512, 0, stream>>>(Qhp, Khp, Vtp, X);
    cvt_f32_bf16<<<1024, 256, 0, stream>>>(Wo, WX, nW / 4);
    gemm_bt<0, 0><<<gg, 256, 0, stream>>>(X, nullptr, WX, bo, out, nullptr, M, DIM, DIM, 1.0f);
  }
}